// Round 7
// baseline (192.416 us; speedup 1.0000x reference)
//
#include <hip/hip_runtime.h>

// Trilinear warp (SpatialTransformer): vol [B=2,D=160,H=192,W=160,C=2] f32,
// flow [B,D,H,W,3] f32 ('ij'). Output f32, same shape as vol.
//
// R6 lesson: LDS staging cut L2 gather requests 5x but collapsed occupancy
// (79.9KB LDS x 256-thr blocks => 8 waves/CU => latency-bound, 153us).
// R7 fix: SAME tile + SAME LDS region, but 1024-thread blocks (16 waves,
// 2 voxels/thread). 2 blocks/CU = 159,744B LDS (fits 160KB, proven by R6's
// 2-resident blocks) => up to 32 waves/CU. Flow loads issued before staging
// (overlap), staging split into issue-5-loads / write-5 (T14).

constexpr int Bb = 2, Dd = 160, Hh = 192, Ww = 160;
constexpr int HW  = Hh * Ww;          // 30720
constexpr int VOX = Dd * HW;          // 4,915,200 voxels per batch

constexpr int TD = 8,  TH = 16, TW = 16;   // output tile (2048 voxels)
constexpr int RD = TD + 8;                 // 16  staged region (halo 4)
constexpr int RH = TH + 8;                 // 24
constexpr int RW = TW + 8;                 // 24  (extent always even)
constexpr int RWP = 26;                    // padded LDS row stride (float2)
constexpr int QROW = RW / 2;               // 12 float4 quads per row
constexpr int NQ = RD * RH * QROW;         // 4608 staged quads
constexpr int ND = Dd / TD, NH = Hh / TH, NW = Ww / TW;   // 20, 12, 10
constexpr int NBLK = Bb * ND * NH * NW;                   // 4800
constexpr int BLOCK = 1024;                // 16 waves; 2 voxels per thread
constexpr size_t LDS_BYTES = (size_t)RD * RH * RWP * sizeof(float2);  // 79872

__global__ __launch_bounds__(BLOCK, 8)   // 8 waves/SIMD -> VGPR <= 64 -> 2 blocks/CU
void SpatialTransformer_44418551776013_kernel(const float* __restrict__ vol,
                                              const float* __restrict__ flow,
                                              float* __restrict__ out)
{
    extern __shared__ float2 sv[];   // [RD][RH][RWP]
    const int tid = threadIdx.x;

    // bijective XCD swizzle (NBLK % 8 == 0): consecutive tiles (shared halo
    // lines) stay on one XCD's L2.
    constexpr int CPX = NBLK / 8;    // 600
    int bid = (int)(blockIdx.x % 8) * CPX + (int)(blockIdx.x / 8);

    const int bw = bid % NW;  bid /= NW;
    const int bh = bid % NH;  bid /= NH;
    const int bd = bid % ND;
    const int b  = bid / ND;
    const int d0 = bd * TD, h0 = bh * TH, w0 = bw * TW;

    // staged region = clip(tile +- 4); extents (block-uniform -> SGPRs)
    const int ox = max(0, d0 - 4), oy = max(0, h0 - 4), oz = max(0, w0 - 4);
    const int ex = min(Dd - 1, d0 + TD + 3) - ox + 1;   // <= RD
    const int ey = min(Hh - 1, h0 + TH + 3) - oy + 1;   // <= RH
    const int ez = min(Ww - 1, w0 + TW + 3) - oz + 1;   // <= RW, even
    const int qz = ez >> 1;

    // compute-thread mapping: (tdg, th, tw); each thread owns td = tdg, tdg+4
    const int tw  = tid & 15;
    const int th  = (tid >> 4) & 15;
    const int tdg = tid >> 8;            // 0..3
    const int h = h0 + th, w = w0 + tw;
    const int gidx1 = ((b * Dd + d0 + tdg) * Hh + h) * Ww + w;
    const int gidx2 = gidx1 + 4 * HW;

    // ---- flow loads first: independent of staging, latency overlaps it ----
    const float fx1 = flow[(size_t)gidx1 * 3 + 0];
    const float fy1 = flow[(size_t)gidx1 * 3 + 1];
    const float fz1 = flow[(size_t)gidx1 * 3 + 2];
    const float fx2 = flow[(size_t)gidx2 * 3 + 0];
    const float fy2 = flow[(size_t)gidx2 * 3 + 1];
    const float fz2 = flow[(size_t)gidx2 * 3 + 2];

    const float2* __restrict__ v2 =
        reinterpret_cast<const float2*>(vol) + (size_t)b * VOX;

    // ---- stage region: issue all 5 predicated float4 loads, then write ----
    // Load addresses are CLAMPED into the valid extent (duplicate lines on
    // edge blocks only -> L1 hits); LDS slot uses the raw decomposition, so
    // garbage slots are only ones compute never reads.
    float4 rq[5];
    int    slot[5];
    #pragma unroll
    for (int k = 0; k < 5; ++k) {
        const int i = tid + k * BLOCK;
        if (i < NQ) {                       // k<4 always true (folds away)
            int lq = i % QROW;              // compile-time divisors
            const int t  = i / QROW;
            int ly = t % RH;
            int lx = t / RH;
            slot[k] = (lx * RH + ly) * RWP + 2 * lq;   // in-bounds for i<NQ
            lx = min(lx, ex - 1);  ly = min(ly, ey - 1);  lq = min(lq, qz - 1);
            rq[k] = *reinterpret_cast<const float4*>(
                v2 + ((size_t)(ox + lx) * HW + (oy + ly) * Ww + oz + 2 * lq));
        } else {
            slot[k] = -1;
        }
    }
    #pragma unroll
    for (int k = 0; k < 5; ++k)
        if (slot[k] >= 0)
            *reinterpret_cast<float4*>(&sv[slot[k]]) = rq[k];

    __syncthreads();

    const float mx = (float)(Dd - 1), my = (float)(Hh - 1), mz = (float)(Ww - 1);

    auto sample = [&](int d, float fx, float fy, float fz, int gout) {
        // ---- exact reference math ----
        const float lxf = (float)d + fx;
        const float lyf = (float)h + fy;
        const float lzf = (float)w + fz;

        const float l0x = fminf(fmaxf(floorf(lxf), 0.0f), mx);
        const float l0y = fminf(fmaxf(floorf(lyf), 0.0f), my);
        const float l0z = fminf(fmaxf(floorf(lzf), 0.0f), mz);
        const float l1x = fminf(l0x + 1.0f, mx);
        const float l1y = fminf(l0y + 1.0f, my);
        const float l1z = fminf(l0z + 1.0f, mz);

        const float d1x = l1x - lxf, d0x = 1.0f - d1x;
        const float d1y = l1y - lyf, d0y = 1.0f - d1y;
        const float d1z = l1z - lzf, d0z = 1.0f - d1z;

        const int i0x = (int)l0x, i1x = (int)l1x;
        const int i0y = (int)l0y, i1y = (int)l1y;
        const int i0z = (int)l0z, i1z = (int)l1z;

        // region-local coords; in-region iff all within staged extents
        const int a0x = i0x - ox, a1x = i1x - ox;
        const int a0y = i0y - oy, a1y = i1y - oy;
        const int a0z = i0z - oz, a1z = i1z - oz;
        const bool ok = (a0x >= 0) & (a1x < ex) &
                        (a0y >= 0) & (a1y < ey) &
                        (a0z >= 0) & (a1z < ez);

        float2 c000, c001, c010, c011, c100, c101, c110, c111;
        if (ok) {   // common path (P(miss) ~ 1.9e-4/voxel): 8 LDS reads
            const int r00 = (a0x * RH + a0y) * RWP;
            const int r01 = (a0x * RH + a1y) * RWP;
            const int r10 = (a1x * RH + a0y) * RWP;
            const int r11 = (a1x * RH + a1y) * RWP;
            c000 = sv[r00 + a0z];  c001 = sv[r00 + a1z];
            c010 = sv[r01 + a0z];  c011 = sv[r01 + a1z];
            c100 = sv[r10 + a0z];  c101 = sv[r10 + a1z];
            c110 = sv[r11 + a0z];  c111 = sv[r11 + a1z];
        } else {    // rare exact global fallback (identical indices/math)
            const int rx0 = i0x * HW, rx1 = i1x * HW;
            const int ry0 = i0y * Ww, ry1 = i1y * Ww;
            c000 = v2[rx0 + ry0 + i0z];  c001 = v2[rx0 + ry0 + i1z];
            c010 = v2[rx0 + ry1 + i0z];  c011 = v2[rx0 + ry1 + i1z];
            c100 = v2[rx1 + ry0 + i0z];  c101 = v2[rx1 + ry0 + i1z];
            c110 = v2[rx1 + ry1 + i0z];  c111 = v2[rx1 + ry1 + i1z];
        }

        // corner bit 0 -> lower index, weight d1; bit 1 -> upper, weight d0
        const float w000 = d1x * d1y * d1z;
        const float w001 = d1x * d1y * d0z;
        const float w010 = d1x * d0y * d1z;
        const float w011 = d1x * d0y * d0z;
        const float w100 = d0x * d1y * d1z;
        const float w101 = d0x * d1y * d0z;
        const float w110 = d0x * d0y * d1z;
        const float w111 = d0x * d0y * d0z;

        float oxv = w000 * c000.x;
        float oyv = w000 * c000.y;
        oxv = fmaf(w001, c001.x, oxv);  oyv = fmaf(w001, c001.y, oyv);
        oxv = fmaf(w010, c010.x, oxv);  oyv = fmaf(w010, c010.y, oyv);
        oxv = fmaf(w011, c011.x, oxv);  oyv = fmaf(w011, c011.y, oyv);
        oxv = fmaf(w100, c100.x, oxv);  oyv = fmaf(w100, c100.y, oyv);
        oxv = fmaf(w101, c101.x, oxv);  oyv = fmaf(w101, c101.y, oyv);
        oxv = fmaf(w110, c110.x, oxv);  oyv = fmaf(w110, c110.y, oyv);
        oxv = fmaf(w111, c111.x, oxv);  oyv = fmaf(w111, c111.y, oyv);

        reinterpret_cast<float2*>(out)[gout] = make_float2(oxv, oyv);
    };

    sample(d0 + tdg,     fx1, fy1, fz1, gidx1);
    sample(d0 + tdg + 4, fx2, fy2, fz2, gidx2);
}

extern "C" void kernel_launch(void* const* d_in, const int* in_sizes, int n_in,
                              void* d_out, int out_size, void* d_ws, size_t ws_size,
                              hipStream_t stream)
{
    const float* vol  = (const float*)d_in[0];   // [2,160,192,160,2] f32
    const float* flow = (const float*)d_in[1];   // [2,160,192,160,3] f32
    float* out = (float*)d_out;                  // [2,160,192,160,2] f32

    SpatialTransformer_44418551776013_kernel<<<NBLK, BLOCK, LDS_BYTES, stream>>>(vol, flow, out);
}

// Round 8
// 90.203 us; speedup vs baseline: 2.1331x; 2.1331x over previous
//
#include <hip/hip_runtime.h>

// Trilinear warp (SpatialTransformer): vol [B=2,D=160,H=192,W=160,C=2] f32,
// flow [B,D,H,W,3] f32 ('ij'). Output f32, same shape as vol.
//
// R7 lesson: 1024-thr + 2 blocks/CU occupancy fix worked (83%), but the
// 5-wide register staging burst spilled under the 64-VGPR cap ->
// WRITE_SIZE 77->422 MB of scratch write-back. R8: same structure, simple
// one-float4-live staging loop (unroll 1); 32 waves/CU TLP hides the chain.

constexpr int Bb = 2, Dd = 160, Hh = 192, Ww = 160;
constexpr int HW  = Hh * Ww;          // 30720
constexpr int VOX = Dd * HW;          // 4,915,200 voxels per batch

constexpr int TD = 8,  TH = 16, TW = 16;   // output tile (2048 voxels)
constexpr int RD = TD + 8;                 // 16  staged region (halo 4)
constexpr int RH = TH + 8;                 // 24
constexpr int RW = TW + 8;                 // 24  (extent always even)
constexpr int RWP = 26;                    // padded LDS row stride (float2)
constexpr int QROW = RW / 2;               // 12 float4 quads per row
constexpr int NQ = RD * RH * QROW;         // 4608 staged quads
constexpr int ND = Dd / TD, NH = Hh / TH, NW = Ww / TW;   // 20, 12, 10
constexpr int NBLK = Bb * ND * NH * NW;                   // 4800
constexpr int BLOCK = 1024;                // 16 waves; 2 voxels per thread
constexpr size_t LDS_BYTES = (size_t)RD * RH * RWP * sizeof(float2);  // 79872

__global__ __launch_bounds__(BLOCK, 8)   // 8 waves/EU => VGPR<=64 => 2 blocks/CU
void SpatialTransformer_44418551776013_kernel(const float* __restrict__ vol,
                                              const float* __restrict__ flow,
                                              float* __restrict__ out)
{
    extern __shared__ float2 sv[];   // [RD][RH][RWP]
    const int tid = threadIdx.x;

    // bijective XCD swizzle (NBLK % 8 == 0): neighboring tiles (shared halo
    // lines) land on the same XCD's L2. Validated R7: FETCH 222->153 MB.
    constexpr int CPX = NBLK / 8;    // 600
    int bid = (int)(blockIdx.x % 8) * CPX + (int)(blockIdx.x / 8);

    const int bw = bid % NW;  bid /= NW;
    const int bh = bid % NH;  bid /= NH;
    const int bd = bid % ND;
    const int b  = bid / ND;
    const int d0 = bd * TD, h0 = bh * TH, w0 = bw * TW;

    // staged region = clip(tile +- 4); block-uniform -> SGPRs
    const int ox = max(0, d0 - 4), oy = max(0, h0 - 4), oz = max(0, w0 - 4);
    const int ex = min(Dd - 1, d0 + TD + 3) - ox + 1;   // <= RD
    const int ey = min(Hh - 1, h0 + TH + 3) - oy + 1;   // <= RH
    const int ez = min(Ww - 1, w0 + TW + 3) - oz + 1;   // <= RW, even
    const int qz = ez >> 1;

    // compute mapping: (tdg, th, tw); thread owns td = tdg and tdg+4
    const int tw  = tid & 15;
    const int th  = (tid >> 4) & 15;
    const int tdg = tid >> 8;            // 0..3
    const int h = h0 + th, w = w0 + tw;
    const int gidx1 = ((b * Dd + d0 + tdg) * Hh + h) * Ww + w;
    const int gidx2 = gidx1 + 4 * HW;

    // flow loads first: independent of staging, in flight during it (6 VGPR)
    const float fx1 = flow[(size_t)gidx1 * 3 + 0];
    const float fy1 = flow[(size_t)gidx1 * 3 + 1];
    const float fz1 = flow[(size_t)gidx1 * 3 + 2];
    const float fx2 = flow[(size_t)gidx2 * 3 + 0];
    const float fy2 = flow[(size_t)gidx2 * 3 + 1];
    const float fz2 = flow[(size_t)gidx2 * 3 + 2];

    const float2* __restrict__ v2 =
        reinterpret_cast<const float2*>(vol) + (size_t)b * VOX;

    // ---- stage region into LDS: ONE float4 live per thread (no spill) ----
    // Load addresses clamped into valid extent (edge blocks duplicate lines
    // -> L1 hits); LDS slot from raw decomposition, over-extent slots are
    // written with duplicates but never read (in-region test below).
    #pragma unroll 1
    for (int i = tid; i < NQ; i += BLOCK) {   // 4-5 iterations
        int lq = i % QROW;                    // compile-time divisors
        const int t  = i / QROW;
        int ly = t % RH;
        int lx = t / RH;
        const int s = (lx * RH + ly) * RWP + 2 * lq;
        lx = min(lx, ex - 1);  ly = min(ly, ey - 1);  lq = min(lq, qz - 1);
        const float4 v = *reinterpret_cast<const float4*>(
            v2 + ((size_t)(ox + lx) * HW + (oy + ly) * Ww + oz + 2 * lq));
        *reinterpret_cast<float4*>(&sv[s]) = v;
    }
    __syncthreads();

    const float mx = (float)(Dd - 1), my = (float)(Hh - 1), mz = (float)(Ww - 1);

    auto sample = [&](int d, float fx, float fy, float fz, int gout) {
        // ---- exact reference math ----
        const float lxf = (float)d + fx;
        const float lyf = (float)h + fy;
        const float lzf = (float)w + fz;

        const float l0x = fminf(fmaxf(floorf(lxf), 0.0f), mx);
        const float l0y = fminf(fmaxf(floorf(lyf), 0.0f), my);
        const float l0z = fminf(fmaxf(floorf(lzf), 0.0f), mz);
        const float l1x = fminf(l0x + 1.0f, mx);
        const float l1y = fminf(l0y + 1.0f, my);
        const float l1z = fminf(l0z + 1.0f, mz);

        const float d1x = l1x - lxf, d0x = 1.0f - d1x;
        const float d1y = l1y - lyf, d0y = 1.0f - d1y;
        const float d1z = l1z - lzf, d0z = 1.0f - d1z;

        const int i0x = (int)l0x, i1x = (int)l1x;
        const int i0y = (int)l0y, i1y = (int)l1y;
        const int i0z = (int)l0z, i1z = (int)l1z;

        // region-local coords; in-region iff all within staged extents
        const int a0x = i0x - ox, a1x = i1x - ox;
        const int a0y = i0y - oy, a1y = i1y - oy;
        const int a0z = i0z - oz, a1z = i1z - oz;
        const bool ok = (a0x >= 0) & (a1x < ex) &
                        (a0y >= 0) & (a1y < ey) &
                        (a0z >= 0) & (a1z < ez);

        float2 c000, c001, c010, c011, c100, c101, c110, c111;
        if (ok) {   // common path (P(miss) ~ 1.9e-4/voxel): 8 LDS reads
            const int r00 = (a0x * RH + a0y) * RWP;
            const int r01 = (a0x * RH + a1y) * RWP;
            const int r10 = (a1x * RH + a0y) * RWP;
            const int r11 = (a1x * RH + a1y) * RWP;
            c000 = sv[r00 + a0z];  c001 = sv[r00 + a1z];
            c010 = sv[r01 + a0z];  c011 = sv[r01 + a1z];
            c100 = sv[r10 + a0z];  c101 = sv[r10 + a1z];
            c110 = sv[r11 + a0z];  c111 = sv[r11 + a1z];
        } else {    // rare exact global fallback (identical indices/math)
            const int rx0 = i0x * HW, rx1 = i1x * HW;
            const int ry0 = i0y * Ww, ry1 = i1y * Ww;
            c000 = v2[rx0 + ry0 + i0z];  c001 = v2[rx0 + ry0 + i1z];
            c010 = v2[rx0 + ry1 + i0z];  c011 = v2[rx0 + ry1 + i1z];
            c100 = v2[rx1 + ry0 + i0z];  c101 = v2[rx1 + ry0 + i1z];
            c110 = v2[rx1 + ry1 + i0z];  c111 = v2[rx1 + ry1 + i1z];
        }

        // corner bit 0 -> lower index, weight d1; bit 1 -> upper, weight d0
        const float w000 = d1x * d1y * d1z;
        const float w001 = d1x * d1y * d0z;
        const float w010 = d1x * d0y * d1z;
        const float w011 = d1x * d0y * d0z;
        const float w100 = d0x * d1y * d1z;
        const float w101 = d0x * d1y * d0z;
        const float w110 = d0x * d0y * d1z;
        const float w111 = d0x * d0y * d0z;

        float oxv = w000 * c000.x;
        float oyv = w000 * c000.y;
        oxv = fmaf(w001, c001.x, oxv);  oyv = fmaf(w001, c001.y, oyv);
        oxv = fmaf(w010, c010.x, oxv);  oyv = fmaf(w010, c010.y, oyv);
        oxv = fmaf(w011, c011.x, oxv);  oyv = fmaf(w011, c011.y, oyv);
        oxv = fmaf(w100, c100.x, oxv);  oyv = fmaf(w100, c100.y, oyv);
        oxv = fmaf(w101, c101.x, oxv);  oyv = fmaf(w101, c101.y, oyv);
        oxv = fmaf(w110, c110.x, oxv);  oyv = fmaf(w110, c110.y, oyv);
        oxv = fmaf(w111, c111.x, oxv);  oyv = fmaf(w111, c111.y, oyv);

        reinterpret_cast<float2*>(out)[gout] = make_float2(oxv, oyv);
    };

    sample(d0 + tdg,     fx1, fy1, fz1, gidx1);
    sample(d0 + tdg + 4, fx2, fy2, fz2, gidx2);
}

extern "C" void kernel_launch(void* const* d_in, const int* in_sizes, int n_in,
                              void* d_out, int out_size, void* d_ws, size_t ws_size,
                              hipStream_t stream)
{
    const float* vol  = (const float*)d_in[0];   // [2,160,192,160,2] f32
    const float* flow = (const float*)d_in[1];   // [2,160,192,160,3] f32
    float* out = (float*)d_out;                  // [2,160,192,160,2] f32

    SpatialTransformer_44418551776013_kernel<<<NBLK, BLOCK, LDS_BYTES, stream>>>(vol, flow, out);
}

// Round 9
// 74.479 us; speedup vs baseline: 2.5835x; 1.2111x over previous
//
#include <hip/hip_runtime.h>

// Trilinear warp (SpatialTransformer): vol [B=2,D=160,H=192,W=160,C=2] f32,
// flow [B,D,H,W,3] f32 ('ij'). Output f32, same shape as vol.
//
// R8 (90us) validated: 8x16x16 tile + halo-4 LDS staging, 1024-thr blocks,
// 2 blocks/CU (32 waves), XCD swizzle. Residual: ~35% stall cycles — the
// per-sample if(ok){LDS}else{global} branch splits the compute phase into
// serial scheduling regions. R9: branchless main path (clamped LDS addrs,
// always-read), both samples in ONE straight-line block, rare lanes fixed
// by a deferred wave-uniform global recompute (exact reference math).

constexpr int Bb = 2, Dd = 160, Hh = 192, Ww = 160;
constexpr int HW  = Hh * Ww;          // 30720
constexpr int VOX = Dd * HW;          // 4,915,200 voxels per batch

constexpr int TD = 8,  TH = 16, TW = 16;   // output tile (2048 voxels)
constexpr int RD = TD + 8;                 // 16  staged region (halo 4)
constexpr int RH = TH + 8;                 // 24
constexpr int RW = TW + 8;                 // 24  (extent always even)
constexpr int RWP = 26;                    // padded LDS row stride (float2)
constexpr int QROW = RW / 2;               // 12 float4 quads per row
constexpr int NQ = RD * RH * QROW;         // 4608 staged quads
constexpr int ND = Dd / TD, NH = Hh / TH, NW = Ww / TW;   // 20, 12, 10
constexpr int NBLK = Bb * ND * NH * NW;                   // 4800
constexpr int BLOCK = 1024;                // 16 waves; 2 voxels per thread
constexpr size_t LDS_BYTES = (size_t)RD * RH * RWP * sizeof(float2);  // 79872

// Exact reference math + global gathers — used only for rare out-of-halo
// lanes (P ~ 1.9e-4/voxel). Identical formulas/op-order to the main path.
__device__ __forceinline__ void sample_global(const float2* __restrict__ v2,
                                              int d, int h, int w,
                                              float fx, float fy, float fz,
                                              float& oxv, float& oyv)
{
    const float mx = (float)(Dd - 1), my = (float)(Hh - 1), mz = (float)(Ww - 1);
    const float lxf = (float)d + fx;
    const float lyf = (float)h + fy;
    const float lzf = (float)w + fz;

    const float l0x = fminf(fmaxf(floorf(lxf), 0.0f), mx);
    const float l0y = fminf(fmaxf(floorf(lyf), 0.0f), my);
    const float l0z = fminf(fmaxf(floorf(lzf), 0.0f), mz);
    const float l1x = fminf(l0x + 1.0f, mx);
    const float l1y = fminf(l0y + 1.0f, my);
    const float l1z = fminf(l0z + 1.0f, mz);

    const float d1x = l1x - lxf, d0x = 1.0f - d1x;
    const float d1y = l1y - lyf, d0y = 1.0f - d1y;
    const float d1z = l1z - lzf, d0z = 1.0f - d1z;

    const int i0x = (int)l0x, i1x = (int)l1x;
    const int i0y = (int)l0y, i1y = (int)l1y;
    const int i0z = (int)l0z, i1z = (int)l1z;

    const int rx0 = i0x * HW, rx1 = i1x * HW;
    const int ry0 = i0y * Ww, ry1 = i1y * Ww;
    const float2 c000 = v2[rx0 + ry0 + i0z], c001 = v2[rx0 + ry0 + i1z];
    const float2 c010 = v2[rx0 + ry1 + i0z], c011 = v2[rx0 + ry1 + i1z];
    const float2 c100 = v2[rx1 + ry0 + i0z], c101 = v2[rx1 + ry0 + i1z];
    const float2 c110 = v2[rx1 + ry1 + i0z], c111 = v2[rx1 + ry1 + i1z];

    const float w000 = d1x * d1y * d1z, w001 = d1x * d1y * d0z;
    const float w010 = d1x * d0y * d1z, w011 = d1x * d0y * d0z;
    const float w100 = d0x * d1y * d1z, w101 = d0x * d1y * d0z;
    const float w110 = d0x * d0y * d1z, w111 = d0x * d0y * d0z;

    oxv = w000 * c000.x;
    oyv = w000 * c000.y;
    oxv = fmaf(w001, c001.x, oxv);  oyv = fmaf(w001, c001.y, oyv);
    oxv = fmaf(w010, c010.x, oxv);  oyv = fmaf(w010, c010.y, oyv);
    oxv = fmaf(w011, c011.x, oxv);  oyv = fmaf(w011, c011.y, oyv);
    oxv = fmaf(w100, c100.x, oxv);  oyv = fmaf(w100, c100.y, oyv);
    oxv = fmaf(w101, c101.x, oxv);  oyv = fmaf(w101, c101.y, oyv);
    oxv = fmaf(w110, c110.x, oxv);  oyv = fmaf(w110, c110.y, oyv);
    oxv = fmaf(w111, c111.x, oxv);  oyv = fmaf(w111, c111.y, oyv);
}

__global__ __launch_bounds__(BLOCK, 8)   // 8 waves/EU => VGPR<=64 => 2 blocks/CU
void SpatialTransformer_44418551776013_kernel(const float* __restrict__ vol,
                                              const float* __restrict__ flow,
                                              float* __restrict__ out)
{
    extern __shared__ float2 sv[];   // [RD][RH][RWP]
    const int tid = threadIdx.x;

    // bijective XCD swizzle (NBLK % 8 == 0): neighboring tiles share halo
    // lines on one XCD's L2. Validated: FETCH 222 -> 132 MB.
    constexpr int CPX = NBLK / 8;    // 600
    int bid = (int)(blockIdx.x % 8) * CPX + (int)(blockIdx.x / 8);

    const int bw = bid % NW;  bid /= NW;
    const int bh = bid % NH;  bid /= NH;
    const int bd = bid % ND;
    const int b  = bid / ND;
    const int d0 = bd * TD, h0 = bh * TH, w0 = bw * TW;

    // staged region = clip(tile +- 4); block-uniform -> SGPRs
    const int ox = max(0, d0 - 4), oy = max(0, h0 - 4), oz = max(0, w0 - 4);
    const int ex = min(Dd - 1, d0 + TD + 3) - ox + 1;   // <= RD
    const int ey = min(Hh - 1, h0 + TH + 3) - oy + 1;   // <= RH
    const int ez = min(Ww - 1, w0 + TW + 3) - oz + 1;   // <= RW, even
    const int qz = ez >> 1;

    // compute mapping: (tdg, th, tw); thread owns td = tdg and tdg+4
    const int tw  = tid & 15;
    const int th  = (tid >> 4) & 15;
    const int tdg = tid >> 8;            // 0..3
    const int h = h0 + th, w = w0 + tw;
    const int gidx1 = ((b * Dd + d0 + tdg) * Hh + h) * Ww + w;
    const int gidx2 = gidx1 + 4 * HW;
    const int dA = d0 + tdg, dB = dA + 4;

    // flow loads first: independent of staging, in flight during it
    const float fx1 = flow[(size_t)gidx1 * 3 + 0];
    const float fy1 = flow[(size_t)gidx1 * 3 + 1];
    const float fz1 = flow[(size_t)gidx1 * 3 + 2];
    const float fx2 = flow[(size_t)gidx2 * 3 + 0];
    const float fy2 = flow[(size_t)gidx2 * 3 + 1];
    const float fz2 = flow[(size_t)gidx2 * 3 + 2];

    const float2* __restrict__ v2 =
        reinterpret_cast<const float2*>(vol) + (size_t)b * VOX;

    // ---- stage region into LDS (R8-proven: one float4 live, no spill) ----
    #pragma unroll 1
    for (int i = tid; i < NQ; i += BLOCK) {   // 4-5 iterations
        int lq = i % QROW;                    // compile-time divisors
        const int t  = i / QROW;
        int ly = t % RH;
        int lx = t / RH;
        const int s = (lx * RH + ly) * RWP + 2 * lq;
        lx = min(lx, ex - 1);  ly = min(ly, ey - 1);  lq = min(lq, qz - 1);
        const float4 v = *reinterpret_cast<const float4*>(
            v2 + ((size_t)(ox + lx) * HW + (oy + ly) * Ww + oz + 2 * lq));
        *reinterpret_cast<float4*>(&sv[s]) = v;
    }
    __syncthreads();

    const float mx = (float)(Dd - 1), my = (float)(Hh - 1), mz = (float)(Ww - 1);

    // Branchless LDS sample: clamp region-local coords into staged extents,
    // always read. ok-lanes get exact values; not-ok lanes get finite
    // garbage overwritten by the deferred fixup.
    auto sample_lds = [&](int d, float fx, float fy, float fz,
                          float& oxv, float& oyv, bool& ok) {
        const float lxf = (float)d + fx;
        const float lyf = (float)h + fy;
        const float lzf = (float)w + fz;

        const float l0x = fminf(fmaxf(floorf(lxf), 0.0f), mx);
        const float l0y = fminf(fmaxf(floorf(lyf), 0.0f), my);
        const float l0z = fminf(fmaxf(floorf(lzf), 0.0f), mz);
        const float l1x = fminf(l0x + 1.0f, mx);
        const float l1y = fminf(l0y + 1.0f, my);
        const float l1z = fminf(l0z + 1.0f, mz);

        const float d1x = l1x - lxf, d0x = 1.0f - d1x;
        const float d1y = l1y - lyf, d0y = 1.0f - d1y;
        const float d1z = l1z - lzf, d0z = 1.0f - d1z;

        const int a0x = (int)l0x - ox, a1x = (int)l1x - ox;
        const int a0y = (int)l0y - oy, a1y = (int)l1y - oy;
        const int a0z = (int)l0z - oz, a1z = (int)l1z - oz;

        ok = (a0x >= 0) & (a1x < ex) &
             (a0y >= 0) & (a1y < ey) &
             (a0z >= 0) & (a1z < ez);

        // clamped coords: in-region lanes unchanged (min/max are no-ops)
        const int c0x = min(max(a0x, 0), ex - 1), c1x = min(max(a1x, 0), ex - 1);
        const int c0y = min(max(a0y, 0), ey - 1), c1y = min(max(a1y, 0), ey - 1);
        const int c0z = min(max(a0z, 0), ez - 1), c1z = min(max(a1z, 0), ez - 1);

        const int r00 = (c0x * RH + c0y) * RWP;
        const int r01 = (c0x * RH + c1y) * RWP;
        const int r10 = (c1x * RH + c0y) * RWP;
        const int r11 = (c1x * RH + c1y) * RWP;
        const float2 c000 = sv[r00 + c0z], c001 = sv[r00 + c1z];
        const float2 c010 = sv[r01 + c0z], c011 = sv[r01 + c1z];
        const float2 c100 = sv[r10 + c0z], c101 = sv[r10 + c1z];
        const float2 c110 = sv[r11 + c0z], c111 = sv[r11 + c1z];

        const float w000 = d1x * d1y * d1z, w001 = d1x * d1y * d0z;
        const float w010 = d1x * d0y * d1z, w011 = d1x * d0y * d0z;
        const float w100 = d0x * d1y * d1z, w101 = d0x * d1y * d0z;
        const float w110 = d0x * d0y * d1z, w111 = d0x * d0y * d0z;

        oxv = w000 * c000.x;
        oyv = w000 * c000.y;
        oxv = fmaf(w001, c001.x, oxv);  oyv = fmaf(w001, c001.y, oyv);
        oxv = fmaf(w010, c010.x, oxv);  oyv = fmaf(w010, c010.y, oyv);
        oxv = fmaf(w011, c011.x, oxv);  oyv = fmaf(w011, c011.y, oyv);
        oxv = fmaf(w100, c100.x, oxv);  oyv = fmaf(w100, c100.y, oyv);
        oxv = fmaf(w101, c101.x, oxv);  oyv = fmaf(w101, c101.y, oyv);
        oxv = fmaf(w110, c110.x, oxv);  oyv = fmaf(w110, c110.y, oyv);
        oxv = fmaf(w111, c111.x, oxv);  oyv = fmaf(w111, c111.y, oyv);
    };

    // ---- both samples: one straight-line block, no divergent CFG ----
    float o1x, o1y, o2x, o2y;
    bool ok1, ok2;
    sample_lds(dA, fx1, fy1, fz1, o1x, o1y, ok1);
    sample_lds(dB, fx2, fy2, fz2, o2x, o2y, ok2);

    // ---- deferred rare fixup (wave-uniform skip ~95% of waves) ----
    if (!__all(ok1 && ok2)) {
        if (!ok1) sample_global(v2, dA, h, w, fx1, fy1, fz1, o1x, o1y);
        if (!ok2) sample_global(v2, dB, h, w, fx2, fy2, fz2, o2x, o2y);
    }

    reinterpret_cast<float2*>(out)[gidx1] = make_float2(o1x, o1y);
    reinterpret_cast<float2*>(out)[gidx2] = make_float2(o2x, o2y);
}

extern "C" void kernel_launch(void* const* d_in, const int* in_sizes, int n_in,
                              void* d_out, int out_size, void* d_ws, size_t ws_size,
                              hipStream_t stream)
{
    const float* vol  = (const float*)d_in[0];   // [2,160,192,160,2] f32
    const float* flow = (const float*)d_in[1];   // [2,160,192,160,3] f32
    float* out = (float*)d_out;                  // [2,160,192,160,2] f32

    SpatialTransformer_44418551776013_kernel<<<NBLK, BLOCK, LDS_BYTES, stream>>>(vol, flow, out);
}